// Round 8
// baseline (272.159 us; speedup 1.0000x reference)
//
#include <hip/hip_runtime.h>
#include <math.h>

// Problem constants: B=4, H=16, L=4096, D=64, S=128
constexpr int BB = 4;
constexpr int HH = 16;
constexpr int LL = 4096;
constexpr int DD = 64;
constexpr int SS = 128;
constexpr int BM = 128;            // rows per group
constexpr int GG = 4;              // groups per block -> 512 rows/block

// R12 post-mortem: full unroll of the 4-group loop let the scheduler stack
// all 3 cross-group xraw prefetches -> allocator pinned 128 VGPR and spilled
// ~700B/thread (WRITE +87MB, FETCH +125MB of scratch, kernel 127us). Twice
// now per-wave ILP prefetch cost spills and never bought time; TLP at 16
// waves/CU is the real latency hider. R13: R12's persistence kept (512
// rows/block, B staged once, ONE barrier, wave-private reduce->fallback->
// write), prefetch deleted (xraw loop-local), g-loop pinned to unroll 1.
constexpr float TAU = 2e-3f;

typedef __attribute__((ext_vector_type(8))) short bf16x8;   // 8 bf16 = 4 VGPR
typedef __attribute__((ext_vector_type(4))) float f32x4;

#define MFMA16 __builtin_amdgcn_mfma_f32_16x16x32_bf16

__device__ __forceinline__ unsigned short f2bf(float v) {
    unsigned u = __float_as_uint(v);
    return (unsigned short)((u + 0x7fffu + ((u >> 16) & 1u)) >> 16);  // RNE
}

// split 8 consecutive floats into hi (bf16 trunc) / lo (bf16 RNE of residual)
__device__ __forceinline__ void split8(const float4 va, const float4 vb,
                                       uint4* hi, uint4* lo) {
    const float v[8] = {va.x, va.y, va.z, va.w, vb.x, vb.y, vb.z, vb.w};
    unsigned hw[4], lw[4];
    #pragma unroll
    for (int p = 0; p < 4; ++p) {
        const unsigned u0 = __float_as_uint(v[2 * p]);
        const unsigned u1 = __float_as_uint(v[2 * p + 1]);
        const unsigned h0 = u0 & 0xffff0000u;
        const unsigned h1 = u1 & 0xffff0000u;
        hw[p] = (u0 >> 16) | h1;
        lw[p] = (unsigned)f2bf(v[2 * p] - __uint_as_float(h0))
              | ((unsigned)f2bf(v[2 * p + 1] - __uint_as_float(h1)) << 16);
    }
    *hi = make_uint4(hw[0], hw[1], hw[2], hw[3]);
    *lo = make_uint4(lw[0], lw[1], lw[2], lw[3]);
}

union FragU { uint4 q; bf16x8 v; };

// ---- pre-kernel: c [H,S,D] fp32 -> ws fragment tiles (hi/lo bf16),
//      plus the out_c passthrough copy (write-once, non-temporal). ----
__global__ __launch_bounds__(256) void convert_c_kernel(
    const float* __restrict__ c, unsigned char* __restrict__ ws,
    float* __restrict__ out_c)
{
    const int sid = blockIdx.x * 256 + threadIdx.x;  // 0..16383
    const int h  = sid >> 10;
    const int r  = sid & 1023;
    const int kt = r >> 9;
    const int ct = (r >> 6) & 7;
    const int ln = r & 63;
    const int cc = ct * 16 + (ln & 15);
    const int k0 = kt * 32 + (ln >> 4) * 8;
    const float4* src = (const float4*)(c + ((size_t)h * SS + cc) * DD + k0);
    uint4 hi, lo;
    split8(src[0], src[1], &hi, &lo);
    unsigned char* base =
        ws + (size_t)h * 32768 + (size_t)(((kt << 3) | ct) * 1024 + ln * 16);
    *(uint4*)(base) = hi;                 // sp=0 (hi) tiles
    *(uint4*)(base + 16384) = lo;         // sp=1 (lo) tiles at +16KB

    // out_c copy: 32768 float4 total = 2 per thread
    const f32x4* __restrict__ s4 = (const f32x4*)c;
    f32x4* __restrict__ d4 = (f32x4*)out_c;
    __builtin_nontemporal_store(s4[sid], d4 + sid);
    __builtin_nontemporal_store(s4[sid + 16384], d4 + sid + 16384);
}

// ================= persistent main kernel (512 rows/block) ==============
template <bool USE_WS>
__global__ __launch_bounds__(256, 2) void quantizer_kernel(
    const float* __restrict__ x,               // [B,H,L,D]
    const float* __restrict__ c,               // [H,S,D]
    const unsigned char* __restrict__ ws,      // pre-converted B tiles
    float* __restrict__ out,                   // [B,H,L,S] one-hot
    float* __restrict__ out_c)                 // [H,S,D] copy of c
{
    __shared__ __align__(16) unsigned char smemB[32768];  // B tiles
    __shared__ int s_res[4][32];               // per-wave row indices
    __shared__ int s_wcnt[4];                  // per-wave flagged count
    __shared__ int s_wlist[4][32];             // per-wave flagged rows

    const int tid = threadIdx.x;
    const int wv = tid >> 6;
    const int lane = tid & 63;
    const int ln15 = lane & 15;
    const long long R0 = (long long)blockIdx.x * (GG * BM);
    const int h = (int)((R0 >> 12) & (HH - 1));   // 4096 rows per (b,h)
    const float* __restrict__ chead = c + (size_t)h * SS * DD;

    // ---- stage B tiles into LDS (once per 512 rows) ----
    if (USE_WS) {
        const unsigned char* wsb = ws + (size_t)h * 32768;
        #pragma unroll
        for (int it = 0; it < 8; ++it) {
            const unsigned off = (unsigned)(wv * 8192 + it * 1024);
            __builtin_amdgcn_global_load_lds(
                (const __attribute__((address_space(1))) unsigned*)
                    (wsb + off + (unsigned)(lane * 16)),
                (__attribute__((address_space(3))) unsigned*)(smemB + off),
                16, 0, 0);
        }
    } else {
        #pragma unroll
        for (int it = 0; it < 4; ++it) {
            const int sid = it * 256 + tid;        // 0..1023
            const int kt = sid >> 9;
            const int ct = (sid >> 6) & 7;
            const int ln = sid & 63;
            const int cc = ct * 16 + (ln & 15);
            const int k0 = kt * 32 + (ln >> 4) * 8;
            const float4* src = (const float4*)(chead + (size_t)cc * DD + k0);
            uint4 hi, lo;
            split8(src[0], src[1], &hi, &lo);
            unsigned char* dst = smemB + ((kt << 3) | ct) * 1024 + ln * 16;
            *(uint4*)dst = hi;
            *(uint4*)(dst + 16384) = lo;
        }
    }

    __syncthreads();   // B tiles visible; the ONLY barrier in this kernel

    #pragma unroll 1   // ONE body copy: keeps live set small (R12 lesson)
    for (int g = 0; g < GG; ++g) {
        const long long rg = R0 + (long long)g * BM;

        if (lane == 0) s_wcnt[wv] = 0;   // wave-private, program-ordered

        // ---- A fragments: global -> registers, split in-reg (loop-local;
        //      TLP across 16 waves/CU hides the load latency) ----
        bf16x8 af[2][2][2];   // [rtb][kt][sp]  sp0=hi sp1=lo
        {
            const int k0 = (lane >> 4) * 8;
            #pragma unroll
            for (int rtb = 0; rtb < 2; ++rtb) {
                const float* xr =
                    x + (size_t)(rg + wv * 32 + rtb * 16 + ln15) * DD + k0;
                #pragma unroll
                for (int kt = 0; kt < 2; ++kt) {
                    const float4 ra = *(const float4*)(xr + kt * 32);
                    const float4 rb = *(const float4*)(xr + kt * 32 + 4);
                    FragU hi, lo;
                    split8(ra, rb, &hi.q, &lo.q);
                    af[rtb][kt][0] = hi.v;
                    af[rtb][kt][1] = lo.v;
                }
            }
        }

        // ---- MFMA: 8 col-tiles, 2x independent 3-deep chains each ----
        float m1[2][4], m2[2][4];
        int   mi_[2][4];
        #pragma unroll
        for (int rtb = 0; rtb < 2; ++rtb)
            #pragma unroll
            for (int r = 0; r < 4; ++r) {
                m1[rtb][r] = -INFINITY; m2[rtb][r] = -INFINITY;
                mi_[rtb][r] = 0;
            }

        #pragma unroll
        for (int ct = 0; ct < 8; ++ct) {
            const unsigned bb = (unsigned)(ct << 10) + (unsigned)(lane * 16);
            const bf16x8 b10 = *(const bf16x8*)(smemB + bb);          // hi kt0
            const bf16x8 b11 = *(const bf16x8*)(smemB + bb + 8192);   // hi kt1
            const bf16x8 b20 = *(const bf16x8*)(smemB + bb + 16384);  // lo kt0
            const bf16x8 b21 = *(const bf16x8*)(smemB + bb + 24576);  // lo kt1
            #pragma unroll
            for (int rtb = 0; rtb < 2; ++rtb) {
                f32x4 a0 = {0.f, 0.f, 0.f, 0.f};
                f32x4 a1 = {0.f, 0.f, 0.f, 0.f};
                a0 = MFMA16(af[rtb][0][1], b10, a0, 0, 0, 0);  // lo*hi kt0
                a0 = MFMA16(af[rtb][0][0], b20, a0, 0, 0, 0);  // hi*lo kt0
                a0 = MFMA16(af[rtb][0][0], b10, a0, 0, 0, 0);  // hi*hi kt0
                a1 = MFMA16(af[rtb][1][1], b11, a1, 0, 0, 0);  // lo*hi kt1
                a1 = MFMA16(af[rtb][1][0], b21, a1, 0, 0, 0);  // hi*lo kt1
                a1 = MFMA16(af[rtb][1][0], b11, a1, 0, 0, 0);  // hi*hi kt1
                #pragma unroll
                for (int r = 0; r < 4; ++r) {
                    const float v = a0[r] + a1[r];
                    const int col = ct * 16 + ln15;
                    m2[rtb][r] =
                        __builtin_amdgcn_fmed3f(m1[rtb][r], v, m2[rtb][r]);
                    if (v > m1[rtb][r]) { m1[rtb][r] = v; mi_[rtb][r] = col; }
                }
            }
        }

        // ---- per-row top-2 reduce across 16 lanes; leaders commit to
        //      wave-private s_res (intra-wave LDS, no barrier needed) ----
        #pragma unroll
        for (int rtb = 0; rtb < 2; ++rtb) {
            int rv[4];
            #pragma unroll
            for (int r = 0; r < 4; ++r) {
                float a1 = m1[rtb][r], a2 = m2[rtb][r];
                int ai = mi_[rtb][r];
                #pragma unroll
                for (int off = 1; off <= 8; off <<= 1) {
                    const float o1 = __shfl_xor(a1, off);
                    const float o2 = __shfl_xor(a2, off);
                    const int   oi = __shfl_xor(ai, off);
                    const bool take = (o1 > a1) || (o1 == a1 && oi < ai);
                    const float n2 = take ? fmaxf(a1, o2) : fmaxf(a2, o1);
                    if (take) { a1 = o1; ai = oi; }
                    a2 = n2;
                }
                rv[r] = ai;
                if (ln15 == 0 && (a1 - a2) < TAU) {
                    const int p = atomicAdd(&s_wcnt[wv], 1);
                    s_wlist[wv][p] = rtb * 16 + (lane >> 4) * 4 + r;
                }
            }
            if (ln15 == 0)
                *(int4*)&s_res[wv][rtb * 16 + (lane >> 4) * 4] =
                    make_int4(rv[0], rv[1], rv[2], rv[3]);
        }

        // ---- wave-local exact fp32 fallback (rare; ~0.3% of rows):
        //      sequential-k fmaf, numerics identical to exact fp32 path ----
        const int cnt = s_wcnt[wv];
        for (int f = 0; f < cnt; ++f) {
            const int local = s_wlist[wv][f];
            const float4* __restrict__ xr =
                (const float4*)(x + (size_t)(rg + wv * 32 + local) * DD);
            const float4* __restrict__ c0 =
                (const float4*)(chead + (size_t)lane * DD);
            const float4* __restrict__ c1 =
                (const float4*)(chead + (size_t)(lane + 64) * DD);
            float s0 = 0.f, s1 = 0.f;
            #pragma unroll
            for (int q = 0; q < 16; ++q) {
                const float4 a = xr[q];
                const float4 b0 = c0[q];
                const float4 b1 = c1[q];
                s0 = fmaf(a.x, b0.x, s0); s0 = fmaf(a.y, b0.y, s0);
                s0 = fmaf(a.z, b0.z, s0); s0 = fmaf(a.w, b0.w, s0);
                s1 = fmaf(a.x, b1.x, s1); s1 = fmaf(a.y, b1.y, s1);
                s1 = fmaf(a.z, b1.z, s1); s1 = fmaf(a.w, b1.w, s1);
            }
            float v = s0; int bi = lane;
            if (s1 > v) { v = s1; bi = lane + 64; }  // strict >: low idx wins
            #pragma unroll
            for (int off = 1; off < 64; off <<= 1) {
                const float ov = __shfl_xor(v, off);
                const int   oi = __shfl_xor(bi, off);
                if (ov > v || (ov == v && oi < bi)) { v = ov; bi = oi; }
            }
            if (lane == 0) s_res[wv][local] = bi;
        }

        // ---- wave-private one-hot write: own 32 rows = 1024 float4,
        //      contiguous 1KB per instruction, NT fire-and-forget ----
        f32x4* __restrict__ op =
            (f32x4*)(out + (size_t)(rg + wv * 32) * SS);
        #pragma unroll
        for (int k = 0; k < 16; ++k) {
            const int i = lane + k * 64;         // 0..1023
            const int am = s_res[wv][i >> 5];
            const int s0 = (i & 31) * 4;
            f32x4 v = {(s0 + 0 == am) ? 1.f : 0.f,
                       (s0 + 1 == am) ? 1.f : 0.f,
                       (s0 + 2 == am) ? 1.f : 0.f,
                       (s0 + 3 == am) ? 1.f : 0.f};
            __builtin_nontemporal_store(v, op + i);
        }
    }

    // ---- copy c to second output region (fallback path only) ----
    if (!USE_WS && blockIdx.x < 128) {
        const float4* __restrict__ src = (const float4*)c;
        float4* __restrict__ dst = (float4*)out_c;
        const int idx = blockIdx.x * 256 + tid;
        dst[idx] = src[idx];
    }
}

extern "C" void kernel_launch(void* const* d_in, const int* in_sizes, int n_in,
                              void* d_out, int out_size, void* d_ws, size_t ws_size,
                              hipStream_t stream) {
    const float* x = (const float*)d_in[0];   // [B,H,L,D] fp32
    const float* c = (const float*)d_in[1];   // [H,S,D]   fp32
    float* out = (float*)d_out;               // onehot [B,H,L,S] then c [H,S,D]
    float* out_c = out + (size_t)BB * HH * LL * SS;

    const int rows = BB * HH * LL;            // 262144
    const int blocks = rows / (GG * BM);      // 512
    const size_t ws_need = (size_t)HH * 32768; // 512 KB

    if (d_ws != nullptr && ws_size >= ws_need) {
        convert_c_kernel<<<64, 256, 0, stream>>>(c, (unsigned char*)d_ws,
                                                 out_c);
        quantizer_kernel<true><<<blocks, 256, 0, stream>>>(
            x, c, (const unsigned char*)d_ws, out, out_c);
    } else {
        quantizer_kernel<false><<<blocks, 256, 0, stream>>>(
            x, c, nullptr, out, out_c);
    }
}

// Round 9
// 202.739 us; speedup vs baseline: 1.3424x; 1.3424x over previous
//
#include <hip/hip_runtime.h>
#include <math.h>

// Problem constants: B=4, H=16, L=4096, D=64, S=128
constexpr int BB = 4;
constexpr int HH = 16;
constexpr int LL = 4096;
constexpr int DD = 64;
constexpr int SS = 128;
constexpr int BM = 128;            // rows per block

// R13 post-mortem: spill persisted (VGPR 128, +64MB WRITE / +133MB FETCH)
// with prefetch removed -> the GG=4 persistent body itself is the spill;
// R10 (GG<=2, same per-group code) allocated 104 clean. All stuck variants
// share LDS staging + the vmcnt(0)-draining barrier. R14: eliminate both.
// ws already holds B in exact per-lane fragment order, so B fragments are
// plain global loads (L1/L2-resident 32KB/head) — byte-identical data, no
// LDS, no barrier, no staging. 2048 one-shot blocks of 4 fully independent
// waves; TLP (16 waves/CU) is the latency hider (R13 lesson).
constexpr float TAU = 2e-3f;

typedef __attribute__((ext_vector_type(8))) short bf16x8;   // 8 bf16 = 4 VGPR
typedef __attribute__((ext_vector_type(4))) float f32x4;

#define MFMA16 __builtin_amdgcn_mfma_f32_16x16x32_bf16

__device__ __forceinline__ unsigned short f2bf(float v) {
    unsigned u = __float_as_uint(v);
    return (unsigned short)((u + 0x7fffu + ((u >> 16) & 1u)) >> 16);  // RNE
}

// split 8 consecutive floats into hi (bf16 trunc) / lo (bf16 RNE of residual)
__device__ __forceinline__ void split8(const float4 va, const float4 vb,
                                       uint4* hi, uint4* lo) {
    const float v[8] = {va.x, va.y, va.z, va.w, vb.x, vb.y, vb.z, vb.w};
    unsigned hw[4], lw[4];
    #pragma unroll
    for (int p = 0; p < 4; ++p) {
        const unsigned u0 = __float_as_uint(v[2 * p]);
        const unsigned u1 = __float_as_uint(v[2 * p + 1]);
        const unsigned h0 = u0 & 0xffff0000u;
        const unsigned h1 = u1 & 0xffff0000u;
        hw[p] = (u0 >> 16) | h1;
        lw[p] = (unsigned)f2bf(v[2 * p] - __uint_as_float(h0))
              | ((unsigned)f2bf(v[2 * p + 1] - __uint_as_float(h1)) << 16);
    }
    *hi = make_uint4(hw[0], hw[1], hw[2], hw[3]);
    *lo = make_uint4(lw[0], lw[1], lw[2], lw[3]);
}

union FragU { uint4 q; bf16x8 v; };

// ---- pre-kernel: c [H,S,D] fp32 -> ws fragment tiles (hi/lo bf16),
//      plus the out_c passthrough copy (write-once, non-temporal).
//      ws layout/head (32KB): tile ((sp<<4)|(kt<<3)|ct)*1KB, lane slot
//      l*16 holds code ct*16+(l&15), k = kt*32+(l>>4)*8+e. ----
__global__ __launch_bounds__(256) void convert_c_kernel(
    const float* __restrict__ c, unsigned char* __restrict__ ws,
    float* __restrict__ out_c)
{
    const int sid = blockIdx.x * 256 + threadIdx.x;  // 0..16383
    const int h  = sid >> 10;
    const int r  = sid & 1023;
    const int kt = r >> 9;
    const int ct = (r >> 6) & 7;
    const int ln = r & 63;
    const int cc = ct * 16 + (ln & 15);
    const int k0 = kt * 32 + (ln >> 4) * 8;
    const float4* src = (const float4*)(c + ((size_t)h * SS + cc) * DD + k0);
    uint4 hi, lo;
    split8(src[0], src[1], &hi, &lo);
    unsigned char* base =
        ws + (size_t)h * 32768 + (size_t)(((kt << 3) | ct) * 1024 + ln * 16);
    *(uint4*)(base) = hi;                 // sp=0 (hi) tiles
    *(uint4*)(base + 16384) = lo;         // sp=1 (lo) tiles at +16KB

    // out_c copy: 32768 float4 total = 2 per thread
    const f32x4* __restrict__ s4 = (const f32x4*)c;
    f32x4* __restrict__ d4 = (f32x4*)out_c;
    __builtin_nontemporal_store(s4[sid], d4 + sid);
    __builtin_nontemporal_store(s4[sid + 16384], d4 + sid + 16384);
}

// ============ barrier-free main kernel: 128 rows/block, no LDS B ========
template <bool USE_WS>
__global__ __launch_bounds__(256, 2) void quantizer_kernel(
    const float* __restrict__ x,               // [B,H,L,D]
    const float* __restrict__ c,               // [H,S,D]
    const unsigned char* __restrict__ ws,      // pre-converted B fragments
    float* __restrict__ out,                   // [B,H,L,S] one-hot
    float* __restrict__ out_c)                 // [H,S,D] copy of c
{
    __shared__ int s_res[4][32];               // per-wave row indices
    __shared__ int s_wcnt[4];                  // per-wave flagged count
    __shared__ int s_wlist[4][32];             // per-wave flagged rows

    const int tid = threadIdx.x;
    const int wv = tid >> 6;
    const int lane = tid & 63;
    const int ln15 = lane & 15;
    const long long r0 = (long long)blockIdx.x * BM;
    const int h = (int)((r0 >> 12) & (HH - 1));   // 4096 rows per (b,h)
    const float* __restrict__ chead = c + (size_t)h * SS * DD;
    const unsigned char* __restrict__ wsb =
        USE_WS ? (ws + (size_t)h * 32768) : nullptr;
    const int k0 = (lane >> 4) * 8;

    if (lane == 0) s_wcnt[wv] = 0;   // wave-private, program-ordered

    // ---- A fragments: global -> registers, split in-reg (no LDS) ----
    bf16x8 af[2][2][2];   // [rtb][kt][sp]  sp0=hi sp1=lo
    #pragma unroll
    for (int rtb = 0; rtb < 2; ++rtb) {
        const float* xr =
            x + (size_t)(r0 + wv * 32 + rtb * 16 + ln15) * DD + k0;
        #pragma unroll
        for (int kt = 0; kt < 2; ++kt) {
            FragU hi, lo;
            split8(*(const float4*)(xr + kt * 32),
                   *(const float4*)(xr + kt * 32 + 4), &hi.q, &lo.q);
            af[rtb][kt][0] = hi.v;
            af[rtb][kt][1] = lo.v;
        }
    }

    // ---- MFMA: 8 col-tiles; B fragments straight from global (ws is in
    //      per-lane fragment order; 32KB/head -> L1/L2 resident) ----
    float m1[2][4], m2[2][4];
    int   mi_[2][4];
    #pragma unroll
    for (int rtb = 0; rtb < 2; ++rtb)
        #pragma unroll
        for (int r = 0; r < 4; ++r) {
            m1[rtb][r] = -INFINITY; m2[rtb][r] = -INFINITY; mi_[rtb][r] = 0;
        }

    #pragma unroll 1   // keep loads inside the loop: no register stacking
    for (int ct = 0; ct < 8; ++ct) {
        bf16x8 b10, b11, b20, b21;
        if constexpr (USE_WS) {
            const unsigned char* bp = wsb + (unsigned)(ct * 1024 + lane * 16);
            b10 = *(const bf16x8*)(bp);            // hi kt0
            b11 = *(const bf16x8*)(bp + 8192);     // hi kt1
            b20 = *(const bf16x8*)(bp + 16384);    // lo kt0
            b21 = *(const bf16x8*)(bp + 24576);    // lo kt1
        } else {
            // split on the fly from c (layout identical to ws tiles)
            const float* cr = chead + (size_t)(ct * 16 + ln15) * DD + k0;
            FragU h0, l0, h1, l1;
            split8(*(const float4*)cr, *(const float4*)(cr + 4),
                   &h0.q, &l0.q);
            split8(*(const float4*)(cr + 32), *(const float4*)(cr + 36),
                   &h1.q, &l1.q);
            b10 = h0.v; b20 = l0.v; b11 = h1.v; b21 = l1.v;
        }
        #pragma unroll
        for (int rtb = 0; rtb < 2; ++rtb) {
            f32x4 a0 = {0.f, 0.f, 0.f, 0.f};
            f32x4 a1 = {0.f, 0.f, 0.f, 0.f};
            a0 = MFMA16(af[rtb][0][1], b10, a0, 0, 0, 0);  // lo*hi kt0
            a0 = MFMA16(af[rtb][0][0], b20, a0, 0, 0, 0);  // hi*lo kt0
            a0 = MFMA16(af[rtb][0][0], b10, a0, 0, 0, 0);  // hi*hi kt0
            a1 = MFMA16(af[rtb][1][1], b11, a1, 0, 0, 0);  // lo*hi kt1
            a1 = MFMA16(af[rtb][1][0], b21, a1, 0, 0, 0);  // hi*lo kt1
            a1 = MFMA16(af[rtb][1][0], b11, a1, 0, 0, 0);  // hi*hi kt1
            #pragma unroll
            for (int r = 0; r < 4; ++r) {
                const float v = a0[r] + a1[r];
                const int col = ct * 16 + ln15;
                // top-2: m2' = med3(m1, v, m2); m1' = max(m1, v)
                m2[rtb][r] = __builtin_amdgcn_fmed3f(m1[rtb][r], v, m2[rtb][r]);
                if (v > m1[rtb][r]) { m1[rtb][r] = v; mi_[rtb][r] = col; }
            }
        }
    }

    // ---- per-row top-2 reduce across 16 lanes; leaders commit to
    //      wave-private s_res (intra-wave LDS, no barrier needed) ----
    #pragma unroll
    for (int rtb = 0; rtb < 2; ++rtb) {
        int rv[4];
        #pragma unroll
        for (int r = 0; r < 4; ++r) {
            float a1 = m1[rtb][r], a2 = m2[rtb][r];
            int ai = mi_[rtb][r];
            #pragma unroll
            for (int off = 1; off <= 8; off <<= 1) {
                const float o1 = __shfl_xor(a1, off);
                const float o2 = __shfl_xor(a2, off);
                const int   oi = __shfl_xor(ai, off);
                const bool take = (o1 > a1) || (o1 == a1 && oi < ai);
                const float n2 = take ? fmaxf(a1, o2) : fmaxf(a2, o1);
                if (take) { a1 = o1; ai = oi; }
                a2 = n2;
            }
            rv[r] = ai;
            if (ln15 == 0 && (a1 - a2) < TAU) {
                const int p = atomicAdd(&s_wcnt[wv], 1);
                s_wlist[wv][p] = rtb * 16 + (lane >> 4) * 4 + r;
            }
        }
        if (ln15 == 0)
            *(int4*)&s_res[wv][rtb * 16 + (lane >> 4) * 4] =
                make_int4(rv[0], rv[1], rv[2], rv[3]);
    }

    // ---- wave-local exact fp32 fallback (rare; ~0.3% of rows):
    //      sequential-k fmaf, numerics identical to exact fp32 path ----
    const int cnt = s_wcnt[wv];
    for (int f = 0; f < cnt; ++f) {
        const int local = s_wlist[wv][f];
        const float4* __restrict__ xr =
            (const float4*)(x + (size_t)(r0 + wv * 32 + local) * DD);
        const float4* __restrict__ c0 =
            (const float4*)(chead + (size_t)lane * DD);
        const float4* __restrict__ c1 =
            (const float4*)(chead + (size_t)(lane + 64) * DD);
        float s0 = 0.f, s1 = 0.f;
        #pragma unroll
        for (int q = 0; q < 16; ++q) {
            const float4 a = xr[q];
            const float4 b0 = c0[q];
            const float4 b1 = c1[q];
            s0 = fmaf(a.x, b0.x, s0); s0 = fmaf(a.y, b0.y, s0);
            s0 = fmaf(a.z, b0.z, s0); s0 = fmaf(a.w, b0.w, s0);
            s1 = fmaf(a.x, b1.x, s1); s1 = fmaf(a.y, b1.y, s1);
            s1 = fmaf(a.z, b1.z, s1); s1 = fmaf(a.w, b1.w, s1);
        }
        float v = s0; int bi = lane;
        if (s1 > v) { v = s1; bi = lane + 64; }      // strict >: low idx wins
        #pragma unroll
        for (int off = 1; off < 64; off <<= 1) {
            const float ov = __shfl_xor(v, off);
            const int   oi = __shfl_xor(bi, off);
            if (ov > v || (ov == v && oi < bi)) { v = ov; bi = oi; }
        }
        if (lane == 0) s_res[wv][local] = bi;
    }

    // ---- wave-private one-hot write: own 32 rows = 16KB contiguous,
    //      NT fire-and-forget (fill-like pattern, proven 6.8 TB/s) ----
    f32x4* __restrict__ op = (f32x4*)(out + (size_t)(r0 + wv * 32) * SS);
    #pragma unroll
    for (int k = 0; k < 16; ++k) {
        const int i = lane + k * 64;         // 0..1023
        const int am = s_res[wv][i >> 5];
        const int s0 = (i & 31) * 4;
        f32x4 v = {(s0 + 0 == am) ? 1.f : 0.f,
                   (s0 + 1 == am) ? 1.f : 0.f,
                   (s0 + 2 == am) ? 1.f : 0.f,
                   (s0 + 3 == am) ? 1.f : 0.f};
        __builtin_nontemporal_store(v, op + i);
    }

    // ---- copy c to second output region (fallback path only) ----
    if (!USE_WS && blockIdx.x < 128) {
        const float4* __restrict__ src = (const float4*)c;
        float4* __restrict__ dst = (float4*)out_c;
        const int idx = blockIdx.x * 256 + tid;
        dst[idx] = src[idx];
    }
}

extern "C" void kernel_launch(void* const* d_in, const int* in_sizes, int n_in,
                              void* d_out, int out_size, void* d_ws, size_t ws_size,
                              hipStream_t stream) {
    const float* x = (const float*)d_in[0];   // [B,H,L,D] fp32
    const float* c = (const float*)d_in[1];   // [H,S,D]   fp32
    float* out = (float*)d_out;               // onehot [B,H,L,S] then c [H,S,D]
    float* out_c = out + (size_t)BB * HH * LL * SS;

    const int rows = BB * HH * LL;            // 262144
    const int blocks = rows / BM;             // 2048
    const size_t ws_need = (size_t)HH * 32768; // 512 KB

    if (d_ws != nullptr && ws_size >= ws_need) {
        convert_c_kernel<<<64, 256, 0, stream>>>(c, (unsigned char*)d_ws,
                                                 out_c);
        quantizer_kernel<true><<<blocks, 256, 0, stream>>>(
            x, c, (const unsigned char*)d_ws, out, out_c);
    } else {
        quantizer_kernel<false><<<blocks, 256, 0, stream>>>(
            x, c, nullptr, out, out_c);
    }
}